// Round 5
// baseline (719.004 us; speedup 1.0000x reference)
//
#include <hip/hip_runtime.h>

#define N_NODES 100000
#define N_EDGES 3200000
#define N_FEAT 512
#define HIDDEN 16
#define N_CLASSES 40

#define SCAN_BLOCKS 98   // ceil(100000/1024)

// histogram CSR-build decomposition
#define NR 7         // node ranges
#define RSH 14       // log2(BINS)
#define BINS 16384   // nodes per range (64 KB LDS)
#define SL 32        // edge slices
#define EPS 100000   // edges per slice (N_EDGES / SL, exact)

// ---------------- phase A: sliced LDS histogram (no global atomics) ----------------

__global__ __launch_bounds__(256) void k_hist(const int* __restrict__ dst,
                                              int* __restrict__ P) {
    __shared__ int lds[BINS];
    int r = blockIdx.x >> 5, s = blockIdx.x & 31;
    int tid = threadIdx.x;
    for (int t = tid; t < BINS; t += 256) lds[t] = 0;
    __syncthreads();
    int lo = r << RSH;
    const int4* dp = reinterpret_cast<const int4*>(dst + s * EPS);
    for (int i = tid; i < EPS / 4; i += 256) {
        int4 d4 = dp[i];
        int u;
        u = d4.x - lo; if ((unsigned)u < BINS) atomicAdd(&lds[u], 1);
        u = d4.y - lo; if ((unsigned)u < BINS) atomicAdd(&lds[u], 1);
        u = d4.z - lo; if ((unsigned)u < BINS) atomicAdd(&lds[u], 1);
        u = d4.w - lo; if ((unsigned)u < BINS) atomicAdd(&lds[u], 1);
    }
    __syncthreads();
    int* Pb = P + (size_t)blockIdx.x * BINS;
    for (int t = tid; t < BINS; t += 256) Pb[t] = lds[t];
}

// ---------------- phase B: cnt = sum over slices; P <- exclusive prefix ----------------

__global__ __launch_bounds__(256) void k_reduce(int* __restrict__ P,
                                                int* __restrict__ cnt) {
    int n = blockIdx.x * 256 + threadIdx.x;
    if (n >= N_NODES) return;
    int r = n >> RSH, b = n & (BINS - 1);
    int* p = P + (size_t)(r * SL) * BINS + b;
    int sum = 0;
    #pragma unroll
    for (int s = 0; s < SL; s++) {
        int v = p[(size_t)s * BINS];
        p[(size_t)s * BINS] = sum;   // exclusive prefix over slices
        sum += v;
    }
    cnt[n] = sum;
}

__global__ void k_dinv(const int* __restrict__ cnt, float* __restrict__ dinv) {
    int i = blockIdx.x * 256 + threadIdx.x;
    if (i < N_NODES) dinv[i] = rsqrtf((float)(cnt[i] + 1));  // +1 self-loop
}

// ---------------- 3-phase exclusive scan of cnt -> row_start ----------------

__global__ __launch_bounds__(1024) void k_scan_a(const int* __restrict__ cnt,
                                                 int* __restrict__ bsum) {
    int tid = threadIdx.x;
    int i = blockIdx.x * 1024 + tid;
    int v = (i < N_NODES) ? cnt[i] : 0;
    #pragma unroll
    for (int off = 32; off >= 1; off >>= 1) v += __shfl_xor(v, off, 64);
    __shared__ int ws[16];
    if ((tid & 63) == 0) ws[tid >> 6] = v;
    __syncthreads();
    if (tid == 0) {
        int s = 0;
        #pragma unroll
        for (int w = 0; w < 16; w++) s += ws[w];
        bsum[blockIdx.x] = s;
    }
}

__global__ __launch_bounds__(128) void k_scan_b(const int* __restrict__ bsum,
                                                int* __restrict__ boff) {
    int tid = threadIdx.x;
    int lane = tid & 63, wv = tid >> 6;
    int v = (tid < SCAN_BLOCKS) ? bsum[tid] : 0;
    int sc = v;
    #pragma unroll
    for (int off = 1; off < 64; off <<= 1) {
        int t = __shfl_up(sc, off, 64);
        if (lane >= off) sc += t;
    }
    __shared__ int wsum[2];
    if (lane == 63) wsum[wv] = sc;
    __syncthreads();
    int pre = (wv == 1) ? wsum[0] : 0;
    if (tid < SCAN_BLOCKS) boff[tid] = pre + sc - v;  // exclusive
}

__global__ __launch_bounds__(1024) void k_scan_c(const int* __restrict__ cnt,
                                                 const int* __restrict__ boff,
                                                 int* __restrict__ row_start) {
    int tid = threadIdx.x;
    int i = blockIdx.x * 1024 + tid;
    int lane = tid & 63, wv = tid >> 6;
    int v = (i < N_NODES) ? cnt[i] : 0;
    int sc = v;
    #pragma unroll
    for (int off = 1; off < 64; off <<= 1) {
        int t = __shfl_up(sc, off, 64);
        if (lane >= off) sc += t;
    }
    __shared__ int wsum[16];
    if (lane == 63) wsum[wv] = sc;
    __syncthreads();
    int pre = 0;
    #pragma unroll
    for (int w = 0; w < 16; w++) pre += (w < wv) ? wsum[w] : 0;
    int excl = boff[blockIdx.x] + pre + sc - v;
    if (i < N_NODES) row_start[i] = excl;
    if (i == N_NODES) row_start[N_NODES] = N_EDGES;
}

// ---------------- phase C: place edges via LDS ordinals (no global atomics) ----------------

__global__ __launch_bounds__(256) void k_build2(const int* __restrict__ src,
                                                const int* __restrict__ dst,
                                                const int* __restrict__ P,
                                                const int* __restrict__ row_start,
                                                const float* __restrict__ dinv,
                                                int2* __restrict__ edge_data) {
    __shared__ int lds[BINS];
    int r = blockIdx.x >> 5, s = blockIdx.x & 31;
    int tid = threadIdx.x;
    const int* Pb = P + (size_t)blockIdx.x * BINS;
    for (int t = tid; t < BINS; t += 256) lds[t] = Pb[t];
    __syncthreads();
    int lo = r << RSH;
    int base = s * EPS;
    const int4* dp = reinterpret_cast<const int4*>(dst + base);
    for (int i = tid; i < EPS / 4; i += 256) {
        int4 d4 = dp[i];
        int e = base + i * 4;
        int dd[4] = {d4.x, d4.y, d4.z, d4.w};
        #pragma unroll
        for (int q = 0; q < 4; q++) {
            int d = dd[q];
            int u = d - lo;
            if ((unsigned)u < BINS) {
                int ord = atomicAdd(&lds[u], 1);
                int sv = src[e + q];
                float nrm = dinv[sv] * dinv[d];
                edge_data[row_start[d] + ord] = make_int2(sv, __float_as_int(nrm));
            }
        }
    }
}

// ---------------- GEMM1: h1[N,16] = x[N,512] @ W1[512,16] ----------------

#define KC 32
#define LDSW 36

__global__ __launch_bounds__(256) void k_gemm1(const float* __restrict__ x,
                                               const float* __restrict__ W1,
                                               float* __restrict__ h1) {
    __shared__ float xs[256 * LDSW];
    int tid = threadIdx.x;
    int row = blockIdx.x * 256 + tid;

    float acc[HIDDEN];
    #pragma unroll
    for (int j = 0; j < HIDDEN; j++) acc[j] = 0.f;

    int s_sub = tid >> 3;  // 0..31
    int s_k4  = tid & 7;   // 0..7

    for (int kc = 0; kc < N_FEAT; kc += KC) {
        __syncthreads();
        #pragma unroll
        for (int l = 0; l < 8; l++) {
            int srow = s_sub + l * 32;
            int grow = blockIdx.x * 256 + srow;
            int gr = grow < N_NODES ? grow : N_NODES - 1;
            float4 v = *reinterpret_cast<const float4*>(
                x + (size_t)gr * N_FEAT + kc + s_k4 * 4);
            *reinterpret_cast<float4*>(&xs[srow * LDSW + s_k4 * 4]) = v;
        }
        __syncthreads();

        const float* Wc = W1 + kc * HIDDEN;  // wave-uniform -> scalar loads
        #pragma unroll
        for (int k4 = 0; k4 < 8; k4++) {
            float4 xv = *reinterpret_cast<const float4*>(&xs[tid * LDSW + k4 * 4]);
            const float* w0 = Wc + (k4 * 4 + 0) * HIDDEN;
            const float* w1 = Wc + (k4 * 4 + 1) * HIDDEN;
            const float* w2 = Wc + (k4 * 4 + 2) * HIDDEN;
            const float* w3 = Wc + (k4 * 4 + 3) * HIDDEN;
            #pragma unroll
            for (int j = 0; j < HIDDEN; j++) {
                acc[j] += xv.x * w0[j];
                acc[j] += xv.y * w1[j];
                acc[j] += xv.z * w2[j];
                acc[j] += xv.w * w3[j];
            }
        }
    }

    if (row < N_NODES) {
        float4* op = reinterpret_cast<float4*>(h1 + (size_t)row * HIDDEN);
        #pragma unroll
        for (int q = 0; q < 4; q++)
            op[q] = make_float4(acc[q*4+0], acc[q*4+1], acc[q*4+2], acc[q*4+3]);
    }
}

// ---------------- CSR aggregation over 16 features ----------------

template <bool RELU>
__global__ __launch_bounds__(256) void k_agg16(const int2* __restrict__ edge_data,
                                               const int* __restrict__ row_start,
                                               const float* __restrict__ dinv,
                                               const float* __restrict__ h,
                                               const float* __restrict__ bias,
                                               float* __restrict__ out) {
    int g = threadIdx.x >> 4, j = threadIdx.x & 15;
    int node = blockIdx.x * 16 + g;
    if (node >= N_NODES) return;
    int beg = row_start[node], end = row_start[node + 1];
    float ds = dinv[node];
    float acc = h[(size_t)node * HIDDEN + j] * (ds * ds);  // self loop
    int i = beg;
    for (; i + 3 < end; i += 4) {
        int2 e0 = edge_data[i + 0];
        int2 e1 = edge_data[i + 1];
        int2 e2 = edge_data[i + 2];
        int2 e3 = edge_data[i + 3];
        float v0 = h[(size_t)e0.x * HIDDEN + j];
        float v1 = h[(size_t)e1.x * HIDDEN + j];
        float v2 = h[(size_t)e2.x * HIDDEN + j];
        float v3 = h[(size_t)e3.x * HIDDEN + j];
        acc += v0 * __int_as_float(e0.y);
        acc += v1 * __int_as_float(e1.y);
        acc += v2 * __int_as_float(e2.y);
        acc += v3 * __int_as_float(e3.y);
    }
    for (; i < end; ++i) {
        int2 ed = edge_data[i];
        acc += h[(size_t)ed.x * HIDDEN + j] * __int_as_float(ed.y);
    }
    if (RELU) acc = fmaxf(acc + bias[j], 0.f);
    out[(size_t)node * HIDDEN + j] = acc;
}

// ---------------- final: out = agg2 @ W2 + b2, log_softmax ----------------

__global__ __launch_bounds__(256) void k_out(const float* __restrict__ agg2,
                                             const float* __restrict__ W2,
                                             const float* __restrict__ b2,
                                             float* __restrict__ out) {
    int r = blockIdx.x * 256 + threadIdx.x;
    if (r >= N_NODES) return;
    float a[HIDDEN];
    const float4* ap = reinterpret_cast<const float4*>(agg2 + (size_t)r * HIDDEN);
    #pragma unroll
    for (int q = 0; q < 4; q++) {
        float4 v = ap[q];
        a[q * 4 + 0] = v.x; a[q * 4 + 1] = v.y;
        a[q * 4 + 2] = v.z; a[q * 4 + 3] = v.w;
    }
    float acc[N_CLASSES];
    #pragma unroll
    for (int jj = 0; jj < N_CLASSES; jj++) acc[jj] = b2[jj];
    #pragma unroll
    for (int kk = 0; kk < HIDDEN; kk++) {
        float av = a[kk];
        #pragma unroll
        for (int jj = 0; jj < N_CLASSES; jj++)
            acc[jj] += av * W2[kk * N_CLASSES + jj];  // uniform -> scalar loads
    }
    float m = -1e30f;
    #pragma unroll
    for (int jj = 0; jj < N_CLASSES; jj++) m = fmaxf(m, acc[jj]);
    float sum = 0.f;
    #pragma unroll
    for (int jj = 0; jj < N_CLASSES; jj++) sum += __expf(acc[jj] - m);
    float l = m + __logf(sum);
    float4* op = reinterpret_cast<float4*>(out + (size_t)r * N_CLASSES);
    #pragma unroll
    for (int q = 0; q < N_CLASSES / 4; q++) {
        op[q] = make_float4(acc[q*4+0] - l, acc[q*4+1] - l,
                            acc[q*4+2] - l, acc[q*4+3] - l);
    }
}

// ---------------- launch ----------------

extern "C" void kernel_launch(void* const* d_in, const int* in_sizes, int n_in,
                              void* d_out, int out_size, void* d_ws, size_t ws_size,
                              hipStream_t stream) {
    const float* x  = (const float*)d_in[0];
    const int*   ei = (const int*)d_in[1];   // int64 ref -> int32 in harness
    const float* W1 = (const float*)d_in[2];
    const float* b1 = (const float*)d_in[3];
    const float* W2 = (const float*)d_in[4];
    const float* b2 = (const float*)d_in[5];
    const int* src = ei;
    const int* dst = ei + N_EDGES;
    float* out = (float*)d_out;

    // workspace layout (256B-aligned). P (14.7 MB) is dead after k_build2,
    // so h1/rbuf/agg2 alias its memory. Total ~46 MB.
    char* ws = (char*)d_ws;
    size_t off = 0;
    auto alloc = [&](size_t bytes) {
        size_t o = off; off = (off + bytes + 255) & ~(size_t)255; return o;
    };
    float* dinv      = (float*)(ws + alloc(sizeof(float) * N_NODES));
    int*   cnt       = (int*)  (ws + alloc(sizeof(int) * N_NODES));
    int*   row_start = (int*)  (ws + alloc(sizeof(int) * (N_NODES + 1)));
    int*   bsum      = (int*)  (ws + alloc(sizeof(int) * SCAN_BLOCKS));
    int*   boff      = (int*)  (ws + alloc(sizeof(int) * SCAN_BLOCKS));
    int2*  edge_data = (int2*) (ws + alloc(sizeof(int2) * N_EDGES));
    size_t pBytes = sizeof(int) * (size_t)NR * SL * BINS;          // 14,680,064
    size_t hBytes = sizeof(float) * (size_t)N_NODES * HIDDEN * 3;  // 19,200,000
    char*  big = ws + alloc(pBytes > hBytes ? pBytes : hBytes);
    int*   P    = (int*)big;
    float* h1   = (float*)big;
    float* rbuf = h1 + (size_t)N_NODES * HIDDEN;
    float* agg2 = rbuf + (size_t)N_NODES * HIDDEN;

    const int nodeBlocks = (N_NODES + 255) / 256;   // 391
    const int histBlocks = NR * SL;                 // 224
    const int aggBlocks  = (N_NODES + 15) / 16;     // 6250

    k_hist<<<histBlocks, 256, 0, stream>>>(dst, P);
    k_reduce<<<nodeBlocks, 256, 0, stream>>>(P, cnt);
    k_dinv<<<nodeBlocks, 256, 0, stream>>>(cnt, dinv);
    k_scan_a<<<SCAN_BLOCKS, 1024, 0, stream>>>(cnt, bsum);
    k_scan_b<<<1, 128, 0, stream>>>(bsum, boff);
    k_scan_c<<<SCAN_BLOCKS, 1024, 0, stream>>>(cnt, boff, row_start);
    k_build2<<<histBlocks, 256, 0, stream>>>(src, dst, P, row_start, dinv, edge_data);

    k_gemm1<<<nodeBlocks, 256, 0, stream>>>(x, W1, h1);
    k_agg16<true><<<aggBlocks, 256, 0, stream>>>(edge_data, row_start, dinv, h1, b1, rbuf);
    k_agg16<false><<<aggBlocks, 256, 0, stream>>>(edge_data, row_start, dinv, rbuf, nullptr, agg2);
    k_out<<<nodeBlocks, 256, 0, stream>>>(agg2, W2, b2, out);
}